// Round 15
// baseline (80.704 us; speedup 1.0000x reference)
//
#include <hip/hip_runtime.h>
#include <math.h>

#define CDIM 1024
#define RDIM 100
#define NBAGS 8192
#define RPAD 112            // 7 r-tiles of 16
#define BPB 16              // bags per block
#define NBLK (NBAGS / BPB)  // 512
#define WAVES 8

typedef float floatx4 __attribute__((ext_vector_type(4)));
typedef short bf16x8 __attribute__((ext_vector_type(8)));

__device__ __forceinline__ float dot4(float4 a, float4 b) {
    return a.x * b.x + a.y * b.y + a.z * b.z + a.w * b.w;
}

// fp32 -> bf16 round-to-nearest-even
__device__ __forceinline__ unsigned short f2bf(float f) {
    unsigned int u = __builtin_bit_cast(unsigned int, f);
    u += 0x7FFFu + ((u >> 16) & 1u);
    return (unsigned short)(u >> 16);
}

#define LOADROW(D0, D1, D2, D3, ri)                                          \
    {                                                                        \
        const float4* p_ = (const float4*)(X + (size_t)(ri) * CDIM);         \
        D0 = p_[lane];       D1 = p_[lane + 64];                             \
        D2 = p_[lane + 128]; D3 = p_[lane + 192];                            \
    }

// Online-softmax update with one row held in named registers.
#define COMPUTE_ROW(A0, A1, A2, A3)                                          \
    {                                                                        \
        float p = dot4(A0, c0) + dot4(A1, c1) + dot4(A2, c2) + dot4(A3, c3); \
        p += __shfl_xor(p, 1);                                               \
        p += __shfl_xor(p, 2);                                               \
        p += __shfl_xor(p, 4);                                               \
        p += __shfl_xor(p, 8);                                               \
        p += __shfl_xor(p, 16);                                              \
        p += __shfl_xor(p, 32);                                              \
        const float newm = fmaxf(m, p);                                      \
        const float corr = __expf(m - newm);  /* 0 on first row */           \
        const float wgt  = __expf(p - newm);                                 \
        denom = fmaf(denom, corr, wgt);                                      \
        a0.x = fmaf(a0.x, corr, wgt * A0.x); a0.y = fmaf(a0.y, corr, wgt * A0.y); \
        a0.z = fmaf(a0.z, corr, wgt * A0.z); a0.w = fmaf(a0.w, corr, wgt * A0.w); \
        a1.x = fmaf(a1.x, corr, wgt * A1.x); a1.y = fmaf(a1.y, corr, wgt * A1.y); \
        a1.z = fmaf(a1.z, corr, wgt * A1.z); a1.w = fmaf(a1.w, corr, wgt * A1.w); \
        a2.x = fmaf(a2.x, corr, wgt * A2.x); a2.y = fmaf(a2.y, corr, wgt * A2.y); \
        a2.z = fmaf(a2.z, corr, wgt * A2.z); a2.w = fmaf(a2.w, corr, wgt * A2.w); \
        a3.x = fmaf(a3.x, corr, wgt * A3.x); a3.y = fmaf(a3.y, corr, wgt * A3.y); \
        a3.z = fmaf(a3.z, corr, wgt * A3.z); a3.w = fmaf(a3.w, corr, wgt * A3.w); \
        m = newm;                                                            \
    }

// Prep kernel: build PW (W in B-fragment order, bf16, zero-padded rows
// 100..111). PW[((kc*7+t)*64 + lane)*8 + i] = W[t*16+(lane&15)][kc*32+(lane>>4)*8+i]
__global__ __launch_bounds__(256) void pw_prep(
    const float* __restrict__ W, unsigned short* __restrict__ PW)
{
    const int rr = blockIdx.x;          // 0..111
    const int t  = threadIdx.x;         // channels c = 4t..4t+3
    const int kc  = t >> 3;
    const int sub = (t >> 1) & 3;
    const int i0  = (t & 1) * 4;
    ushort4 o = {0, 0, 0, 0};
    if (rr < RDIM) {
        float4 v = *(const float4*)(W + (size_t)rr * CDIM + t * 4);
        o.x = f2bf(v.x); o.y = f2bf(v.y); o.z = f2bf(v.z); o.w = f2bf(v.w);
    }
    const int tt = rr >> 4, rl = rr & 15;
    *(ushort4*)(PW + ((size_t)(kc * 7 + tt) * 64 + sub * 16 + rl) * 8 + i0) = o;
}

// Fused kernel, merge-free phase 1: block = 16 consecutive bags, 8 waves.
// Each wave sequentially processes WHOLE bags (rows stride-1, 2-deep
// prefetch, online softmax entirely in registers) claimed dynamically via an
// LDS atomic -> no per-bag cross-wave merge, no per-bag __syncthreads (round
// 13's failure: ~2400cy serial merge+prologue x16 bags at 8 waves/CU).
// Finalized bag vectors go bf16 into the swizzled LDS tile bagsm[16][1024].
// Exactly two block-wide barriers total. Phase 2: waves 0-6 each MFMA one
// full-K r-tile from LDS (A, swizzled) x packed PW (B, L2-hot) -> out.
__global__ __launch_bounds__(512) void fused_kernel(
    const float* __restrict__ X,
    const float* __restrict__ Constraints,
    const int* __restrict__ scope,
    const int* __restrict__ rel,
    const unsigned short* __restrict__ PW,
    const float* __restrict__ bias,
    float* __restrict__ out)
{
    __shared__ unsigned short bagsm[BPB][CDIM];   // 32 KB, swizzled
    __shared__ int claim;

    const int lane = threadIdx.x & 63;
    const int w    = threadIdx.x >> 6;
    const int bag0 = blockIdx.x * BPB;

    if (threadIdx.x == 0) claim = WAVES;
    __syncthreads();

    int j = w;   // bag slot within the block (wave-uniform)
    while (j < BPB) {
        const int bag = bag0 + j;
        const int s = scope[2 * bag];
        const int e = scope[2 * bag + 1];

        float4 c0, c1, c2, c3;
        {
            const float4* conp = (const float4*)(Constraints + (size_t)rel[bag] * CDIM);
            c0 = conp[lane]; c1 = conp[lane + 64]; c2 = conp[lane + 128]; c3 = conp[lane + 192];
        }

        float4 a0 = {0.f, 0.f, 0.f, 0.f};
        float4 a1 = {0.f, 0.f, 0.f, 0.f};
        float4 a2 = {0.f, 0.f, 0.f, 0.f};
        float4 a3 = {0.f, 0.f, 0.f, 0.f};
        float m = -INFINITY;
        float denom = 0.f;

        int row = s;
        float4 A0, A1, A2, A3;        // row
        float4 B0, B1, B2, B3;        // row+1
        float4 C0, C1, C2, C3;        // row+2 (rotating)

        LOADROW(A0, A1, A2, A3, row)
        if (row + 1 < e) LOADROW(B0, B1, B2, B3, row + 1)

        for (; row + 2 < e; ++row) {
            LOADROW(C0, C1, C2, C3, row + 2)
            __builtin_amdgcn_sched_barrier(0);
            COMPUTE_ROW(A0, A1, A2, A3)
            A0 = B0; A1 = B1; A2 = B2; A3 = B3;
            B0 = C0; B1 = C1; B2 = C2; B3 = C3;
        }
        if (row + 1 < e) {
            COMPUTE_ROW(A0, A1, A2, A3)
            COMPUTE_ROW(B0, B1, B2, B3)
        } else {
            COMPUTE_ROW(A0, A1, A2, A3)
        }

        // finalize bag wave-locally: normalize, pack bf16, swizzled LDS store.
        // lane holds channels 4*(lane+64q)..+3 in quarter q.
        const float inv = 1.0f / denom;
        const int jx = j & 7;
        {
            ushort4 o;
            o.x = f2bf(a0.x * inv); o.y = f2bf(a0.y * inv);
            o.z = f2bf(a0.z * inv); o.w = f2bf(a0.w * inv);
            const int tq = lane;
            *(ushort4*)((char*)&bagsm[j][0] + ((tq >> 1) ^ jx) * 16 + (tq & 1) * 8) = o;
        }
        {
            ushort4 o;
            o.x = f2bf(a1.x * inv); o.y = f2bf(a1.y * inv);
            o.z = f2bf(a1.z * inv); o.w = f2bf(a1.w * inv);
            const int tq = lane + 64;
            *(ushort4*)((char*)&bagsm[j][0] + ((tq >> 1) ^ jx) * 16 + (tq & 1) * 8) = o;
        }
        {
            ushort4 o;
            o.x = f2bf(a2.x * inv); o.y = f2bf(a2.y * inv);
            o.z = f2bf(a2.z * inv); o.w = f2bf(a2.w * inv);
            const int tq = lane + 128;
            *(ushort4*)((char*)&bagsm[j][0] + ((tq >> 1) ^ jx) * 16 + (tq & 1) * 8) = o;
        }
        {
            ushort4 o;
            o.x = f2bf(a3.x * inv); o.y = f2bf(a3.y * inv);
            o.z = f2bf(a3.z * inv); o.w = f2bf(a3.w * inv);
            const int tq = lane + 192;
            *(ushort4*)((char*)&bagsm[j][0] + ((tq >> 1) ^ jx) * 16 + (tq & 1) * 8) = o;
        }

        // claim next bag (wave-uniform)
        int nj;
        if (lane == 0) nj = atomicAdd(&claim, 1);
        nj = __shfl(nj, 0);
        j = nj;
    }

    __syncthreads();   // bagsm complete

    // ---- Phase 2: waves 0..6 each compute one full-K r-tile of 16 ----
    if (w < 7) {
        const int ln15 = lane & 15;
        const int kgrp = lane >> 4;          // 0..3
        floatx4 acc = (floatx4){0.f, 0.f, 0.f, 0.f};
        const unsigned short* bBase = PW + ((size_t)w * 64 + lane) * 8;

        #pragma unroll 4
        for (int kc = 0; kc < CDIM / 32; ++kc) {
            const int swz = (kc * 4 + kgrp) ^ (ln15 & 7);
            const bf16x8 a = *(const bf16x8*)((const char*)&bagsm[ln15][0] + swz * 16);
            const bf16x8 b = *(const bf16x8*)(bBase + (size_t)kc * 7 * 512);
            acc = __builtin_amdgcn_mfma_f32_16x16x32_bf16(a, b, acc, 0, 0, 0);
        }

        // D: col = lane&15 (r within tile), row = (lane>>4)*4 + reg (bag)
        const int r = w * 16 + ln15;
        if (r < RDIM) {
            const float bv = bias[r];
            const int mbase = kgrp * 4;
            #pragma unroll
            for (int reg = 0; reg < 4; ++reg)
                out[(size_t)(bag0 + mbase + reg) * RDIM + r] = acc[reg] + bv;
        }
    }
}

extern "C" void kernel_launch(void* const* d_in, const int* in_sizes, int n_in,
                              void* d_out, int out_size, void* d_ws, size_t ws_size,
                              hipStream_t stream) {
    const float* X    = (const float*)d_in[0];
    const float* Con  = (const float*)d_in[1];
    const float* W    = (const float*)d_in[2];
    const float* bias = (const float*)d_in[3];
    const int* scope  = (const int*)d_in[4];
    const int* rel    = (const int*)d_in[5];
    float* out = (float*)d_out;

    unsigned short* PW = (unsigned short*)d_ws;   // 112*1024*2 = 0.23 MB

    pw_prep<<<RPAD, 256, 0, stream>>>(W, PW);
    fused_kernel<<<NBLK, 512, 0, stream>>>(X, Con, scope, rel, PW, bias, out);
}

// Round 16
// 67.960 us; speedup vs baseline: 1.1875x; 1.1875x over previous
//
#include <hip/hip_runtime.h>
#include <math.h>

#define CDIM 1024
#define RDIM 100
#define NBAGS 8192
#define RPAD 112   // 7 r-tiles of 16
#define BIGTHR 16  // bags with >= BIGTHR rows are scheduled first

typedef float floatx4 __attribute__((ext_vector_type(4)));
typedef short bf16x8 __attribute__((ext_vector_type(8)));

__device__ __forceinline__ float dot4(float4 a, float4 b) {
    return a.x * b.x + a.y * b.y + a.z * b.z + a.w * b.w;
}

// fp32 -> bf16 round-to-nearest-even
__device__ __forceinline__ unsigned short f2bf(float f) {
    unsigned int u = __builtin_bit_cast(unsigned int, f);
    u += 0x7FFFu + ((u >> 16) & 1u);
    return (unsigned short)(u >> 16);
}

#define LOADROW(D0, D1, D2, D3, ri)                                          \
    {                                                                        \
        const float4* p_ = (const float4*)(X + (size_t)(ri) * CDIM);         \
        D0 = p_[lane];       D1 = p_[lane + 64];                             \
        D2 = p_[lane + 128]; D3 = p_[lane + 192];                            \
    }

// Online-softmax update with one row held in named registers.
#define COMPUTE_ROW(A0, A1, A2, A3)                                          \
    {                                                                        \
        float p = dot4(A0, c0) + dot4(A1, c1) + dot4(A2, c2) + dot4(A3, c3); \
        p += __shfl_xor(p, 1);                                               \
        p += __shfl_xor(p, 2);                                               \
        p += __shfl_xor(p, 4);                                               \
        p += __shfl_xor(p, 8);                                               \
        p += __shfl_xor(p, 16);                                              \
        p += __shfl_xor(p, 32);                                              \
        const float newm = fmaxf(m, p);                                      \
        const float corr = __expf(m - newm);  /* 0 on first row */           \
        const float wgt  = __expf(p - newm);                                 \
        denom = fmaf(denom, corr, wgt);                                      \
        a0.x = fmaf(a0.x, corr, wgt * A0.x); a0.y = fmaf(a0.y, corr, wgt * A0.y); \
        a0.z = fmaf(a0.z, corr, wgt * A0.z); a0.w = fmaf(a0.w, corr, wgt * A0.w); \
        a1.x = fmaf(a1.x, corr, wgt * A1.x); a1.y = fmaf(a1.y, corr, wgt * A1.y); \
        a1.z = fmaf(a1.z, corr, wgt * A1.z); a1.w = fmaf(a1.w, corr, wgt * A1.w); \
        a2.x = fmaf(a2.x, corr, wgt * A2.x); a2.y = fmaf(a2.y, corr, wgt * A2.y); \
        a2.z = fmaf(a2.z, corr, wgt * A2.z); a2.w = fmaf(a2.w, corr, wgt * A2.w); \
        a3.x = fmaf(a3.x, corr, wgt * A3.x); a3.y = fmaf(a3.y, corr, wgt * A3.y); \
        a3.z = fmaf(a3.z, corr, wgt * A3.z); a3.w = fmaf(a3.w, corr, wgt * A3.w); \
        m = newm;                                                            \
    }

// Scheduling prep: partition bags so big bags (straggler candidates) get the
// earliest block slots. Output values are order-independent (each bag is
// processed exactly once with identical math), only the atomic-chosen order
// varies.
__global__ __launch_bounds__(256) void order_prep(
    const int* __restrict__ scope, int* __restrict__ perm, int* __restrict__ counters)
{
    const int bag = blockIdx.x * 256 + threadIdx.x;
    if (bag < NBAGS) {
        const int sz = scope[2 * bag + 1] - scope[2 * bag];
        int pos;
        if (sz >= BIGTHR) pos = atomicAdd(&counters[0], 1);                 // front
        else              pos = NBAGS - 1 - atomicAdd(&counters[1], 1);     // back
        perm[pos] = bag;
    }
}

// Kernel 1 (round-12 structure): one BLOCK (4 waves) per bag, rows striped
// across waves (stride 4), per-wave online-softmax state in registers, 2-deep
// prefetch, LDS merge, coalesced row-major bf16 epilogue. Bag picked via the
// size-ordered perm so straggler bags start in the first dispatch batch.
// Blocks >= NBAGS build PW.
__global__ __launch_bounds__(256) void bag_softmax_kernel(
    const float* __restrict__ X,
    const float* __restrict__ Constraints,
    const int* __restrict__ scope,
    const int* __restrict__ rel,
    const float* __restrict__ W,
    const int* __restrict__ perm,
    unsigned short* __restrict__ bagbuf,
    unsigned short* __restrict__ PW)
{
    const int lane = threadIdx.x & 63;
    const int w    = threadIdx.x >> 6;

    if (blockIdx.x >= NBAGS) {
        // Build PW: one r-row per block (112 blocks), 4 channels per thread.
        // PW[((kc*7+t)*64 + lane)*8 + i] = W[t*16+(lane&15)][kc*32+(lane>>4)*8+i]
        const int rr = blockIdx.x - NBAGS;          // 0..111
        const int t  = threadIdx.x;                 // channels c = 4t..4t+3
        const int kc  = t >> 3;
        const int sub = (t >> 1) & 3;
        const int i0  = (t & 1) * 4;
        ushort4 o = {0, 0, 0, 0};
        if (rr < RDIM) {
            float4 v = *(const float4*)(W + (size_t)rr * CDIM + t * 4);
            o.x = f2bf(v.x); o.y = f2bf(v.y); o.z = f2bf(v.z); o.w = f2bf(v.w);
        }
        const int tt = rr >> 4, rl = rr & 15;
        *(ushort4*)(PW + ((size_t)(kc * 7 + tt) * 64 + sub * 16 + rl) * 8 + i0) = o;
        return;
    }

    __shared__ float4 lds_acc[4][256];
    __shared__ float  lds_m[4];
    __shared__ float  lds_d[4];

    const int bag = perm[blockIdx.x];
    const int s = scope[2 * bag];
    const int e = scope[2 * bag + 1];
    const int r = rel[bag];

    const float4* conp = (const float4*)(Constraints + (size_t)r * CDIM);
    const float4 c0 = conp[lane];
    const float4 c1 = conp[lane + 64];
    const float4 c2 = conp[lane + 128];
    const float4 c3 = conp[lane + 192];

    float4 a0 = {0.f, 0.f, 0.f, 0.f};
    float4 a1 = {0.f, 0.f, 0.f, 0.f};
    float4 a2 = {0.f, 0.f, 0.f, 0.f};
    float4 a3 = {0.f, 0.f, 0.f, 0.f};
    float m = -INFINITY;
    float denom = 0.f;

    int row = s + w;
    if (row < e) {                    // uniform per wave
        float4 A0, A1, A2, A3;        // row
        float4 B0, B1, B2, B3;        // row+4
        float4 C0, C1, C2, C3;        // row+8 (rotating)

        LOADROW(A0, A1, A2, A3, row)
        if (row + 4 < e) LOADROW(B0, B1, B2, B3, row + 4)

        // main loop: runs only while row+8 is a real row (2-deep prefetch)
        for (; row + 8 < e; row += 4) {
            LOADROW(C0, C1, C2, C3, row + 8)
            __builtin_amdgcn_sched_barrier(0);
            COMPUTE_ROW(A0, A1, A2, A3)
            A0 = B0; A1 = B1; A2 = B2; A3 = B3;
            B0 = C0; B1 = C1; B2 = C2; B3 = C3;
        }
        // epilogue: 1 or 2 rows left in registers, zero loads
        if (row + 4 < e) {
            COMPUTE_ROW(A0, A1, A2, A3)
            COMPUTE_ROW(B0, B1, B2, B3)
        } else {
            COMPUTE_ROW(A0, A1, A2, A3)
        }
    }

    if (lane == 0) { lds_m[w] = m; lds_d[w] = denom; }
    lds_acc[w][lane]       = a0;
    lds_acc[w][lane + 64]  = a1;
    lds_acc[w][lane + 128] = a2;
    lds_acc[w][lane + 192] = a3;
    __syncthreads();

    const int t = threadIdx.x;
    const float m0 = lds_m[0], m1 = lds_m[1], m2 = lds_m[2], m3 = lds_m[3];
    const float ms = fmaxf(fmaxf(m0, m1), fmaxf(m2, m3));
    const float f0 = __expf(m0 - ms);   // idle wave: exp(-inf) = 0
    const float f1 = __expf(m1 - ms);
    const float f2 = __expf(m2 - ms);
    const float f3 = __expf(m3 - ms);
    const float dn = f0 * lds_d[0] + f1 * lds_d[1] + f2 * lds_d[2] + f3 * lds_d[3];
    const float inv = 1.0f / dn;

    const float4 v0 = lds_acc[0][t];
    const float4 v1 = lds_acc[1][t];
    const float4 v2 = lds_acc[2][t];
    const float4 v3 = lds_acc[3][t];
    const float ox = (f0 * v0.x + f1 * v1.x + f2 * v2.x + f3 * v3.x) * inv;
    const float oy = (f0 * v0.y + f1 * v1.y + f2 * v2.y + f3 * v3.y) * inv;
    const float oz = (f0 * v0.z + f1 * v1.z + f2 * v2.z + f3 * v3.z) * inv;
    const float ow = (f0 * v0.w + f1 * v1.w + f2 * v2.w + f3 * v3.w) * inv;

    ushort4 o;
    o.x = f2bf(ox); o.y = f2bf(oy); o.z = f2bf(oz); o.w = f2bf(ow);
    *(ushort4*)(bagbuf + (size_t)bag * CDIM + t * 4) = o;   // coalesced
}

// Kernel 2 (round-12): MFMA GEMM, 8-way K-split. Block = 16 bags, 8 waves,
// wave q owns K-chunk [q*128, q*128+128). A gathered from row-major bagbuf;
// B from packed PW (1 KB coalesced loads). Partials reduced through LDS.
__global__ __launch_bounds__(512) void bag_gemm_mfma(
    const unsigned short* __restrict__ bagbuf,
    const unsigned short* __restrict__ PW,
    const float* __restrict__ bias,
    float* __restrict__ out)
{
    const int q    = threadIdx.x >> 6;   // k-chunk 0..7
    const int lane = threadIdx.x & 63;
    const int bag0 = blockIdx.x * 16;
    const int ln15 = lane & 15;
    const int koff = (lane >> 4) * 8;

    __shared__ floatx4 lds[8][7][64];    // 57 KB

    floatx4 acc[7];
    #pragma unroll
    for (int t = 0; t < 7; ++t) acc[t] = (floatx4){0.f, 0.f, 0.f, 0.f};

    const unsigned short* aRow  = bagbuf + (size_t)(bag0 + ln15) * CDIM + koff;
    const unsigned short* bBase = PW + lane * 8;

    #pragma unroll
    for (int i = 0; i < 4; ++i) {
        const int kc = q * 4 + i;
        const bf16x8 a = *(const bf16x8*)(aRow + kc * 32);
        #pragma unroll
        for (int t = 0; t < 7; ++t) {
            const bf16x8 b = *(const bf16x8*)(bBase + (size_t)(kc * 7 + t) * 512);
            acc[t] = __builtin_amdgcn_mfma_f32_16x16x32_bf16(a, b, acc[t], 0, 0, 0);
        }
    }

    #pragma unroll
    for (int t = 0; t < 7; ++t) lds[q][t][lane] = acc[t];
    __syncthreads();

    // 7 tiles x 64 slots = 448 outputs of 4 bags each, over 512 threads.
    const int p = threadIdx.x;
    if (p < 448) {
        const int t    = p >> 6;
        const int slot = p & 63;
        const int r    = t * 16 + (slot & 15);
        if (r < RDIM) {
            floatx4 s = lds[0][t][slot];
            #pragma unroll
            for (int qq = 1; qq < 8; ++qq) s += lds[qq][t][slot];
            const float bv = bias[r];
            const int bagr = bag0 + (slot >> 4) * 4;
            out[(size_t)(bagr + 0) * RDIM + r] = s[0] + bv;
            out[(size_t)(bagr + 1) * RDIM + r] = s[1] + bv;
            out[(size_t)(bagr + 2) * RDIM + r] = s[2] + bv;
            out[(size_t)(bagr + 3) * RDIM + r] = s[3] + bv;
        }
    }
}

extern "C" void kernel_launch(void* const* d_in, const int* in_sizes, int n_in,
                              void* d_out, int out_size, void* d_ws, size_t ws_size,
                              hipStream_t stream) {
    const float* X    = (const float*)d_in[0];
    const float* Con  = (const float*)d_in[1];
    const float* W    = (const float*)d_in[2];
    const float* bias = (const float*)d_in[3];
    const int* scope  = (const int*)d_in[4];
    const int* rel    = (const int*)d_in[5];
    float* out = (float*)d_out;

    unsigned short* bagbuf  = (unsigned short*)d_ws;          // 8192*1024*2 = 16.8 MB
    unsigned short* PW      = bagbuf + (size_t)NBAGS * CDIM;  // 112*1024*2  = 0.23 MB
    int* perm     = (int*)(PW + (size_t)RPAD * CDIM);         // 8192 ints
    int* counters = perm + NBAGS;                             // 2 ints

    hipMemsetAsync(counters, 0, 2 * sizeof(int), stream);
    order_prep<<<NBAGS / 256, 256, 0, stream>>>(scope, perm, counters);
    bag_softmax_kernel<<<NBAGS + RPAD, 256, 0, stream>>>(X, Con, scope, rel, W, perm, bagbuf, PW);
    bag_gemm_mfma<<<NBAGS / 16, 512, 0, stream>>>(bagbuf, PW, bias, out);
}